// Round 2
// baseline (255.528 us; speedup 1.0000x reference)
//
#include <hip/hip_runtime.h>

#define C_CH   1024
#define T_DIM  16384
#define NSTEPS (T_DIM - 16)   // 16368
#define PAD    8
#define TP     (T_DIM + 16)   // padded time length 16400
#define CHUNK  256
#define NCHUNK 64             // 64*256 = 16384 >= 16368
#define WARM   256
#define TILE   64             // cols per LDS tile (256 B per row)

typedef float vf4 __attribute__((ext_vector_type(4)));   // native vec for nontemporal stores

// ws layout:
//   [0, 8*T_DIM*sizeof(double))  : double partial[8][T_DIM]   (1 MiB)
//   [1 MiB, +TP*4)               : float  colmean[TP]
#define WS_CM_OFFSET (8u * T_DIM * sizeof(double))

// ---------------- Kernel 1: per-row-chunk column partial sums ----------------
// 512 blocks x 64 thr (all 256 CUs busy, 2 waves/CU), unroll 16 -> 16 float4
// loads in flight per wave (16 KB) -> BW-bound, ~12 us.
__global__ __launch_bounds__(64) void colsum_partial(const float* __restrict__ inp,
                                                     double* __restrict__ part) {
    int col4 = (blockIdx.x * 64 + threadIdx.x) * 4;   // 0..16380 step 4
    int rc   = blockIdx.y;                            // 0..7 (row chunk of 128)
    const float* p = inp + (size_t)rc * 128 * T_DIM + col4;
    double ax = 0.0, ay = 0.0, az = 0.0, aw = 0.0;
    #pragma unroll 16
    for (int r = 0; r < 128; ++r) {
        float4 v = *(const float4*)(p + (size_t)r * T_DIM);
        ax += (double)v.x; ay += (double)v.y; az += (double)v.z; aw += (double)v.w;
    }
    double* q = part + (size_t)rc * T_DIM + col4;
    q[0] = ax; q[1] = ay; q[2] = az; q[3] = aw;
}

// ---------------- Kernel 2: reduce partials -> padded column means, + tail copy ----------------
__global__ void colmean_tail(const double* __restrict__ part, const float* __restrict__ inp,
                             float* __restrict__ cm, float* __restrict__ out) {
    int i = blockIdx.x * 256 + threadIdx.x;   // 0..16639
    if (i < TP) {
        float v = 0.0f;
        if (i >= PAD && i < T_DIM + PAD) {
            int col = i - PAD;
            double t = 0.0;
            #pragma unroll
            for (int r = 0; r < 8; ++r) t += part[(size_t)r * T_DIM + col];
            v = (float)(t * (1.0 / 1024.0));        // /1024 is exact
        }
        cm[i] = v;
    }
    if (i < C_CH * 16) {                       // tail columns NSTEPS..T_DIM-1
        int c = i >> 4, j = i & 15;
        size_t idx = (size_t)c * T_DIM + NSTEPS + j;
        out[idx] = inp[idx];
    }
}

// ---------------- scan kernel helpers ----------------
// Stage one [64 rows][64 cols] tile into LDS via global_load_lds (size=16).
// Per instruction: 64 lanes x 16B = 1 KB = 4 consecutive rows' 256 B segments.
// LDS dest is linear (required); the XOR bank-swizzle (chunk ^ (row&7)) is
// applied on the per-lane GLOBAL source address instead (G21/m173 pattern),
// and the same XOR is applied on the ds_read side.
__device__ __forceinline__ void stage_tile(const float* __restrict__ inp, int ch0,
                                           int col0, float* dst, int lane) {
    const int sub = lane >> 4;        // row within quad: 0..3
    const int ci  = lane & 15;        // 16B-chunk index within row: 0..15
    #pragma unroll
    for (int ii = 0; ii < 16; ++ii) {
        int r   = 4 * ii + sub;                       // tile row = channel offset
        int q   = ci ^ (r & 7);                       // logical chunk for this slot
        int col = col0 + q * 4;                       // global float column
        col = min(max(col, 0), T_DIM - 4);            // clamp (edges: values unused/zeroed)
        const float* src = inp + (size_t)(ch0 + r) * T_DIM + col;
        __builtin_amdgcn_global_load_lds(
            (const __attribute__((address_space(1))) void*)src,
            (__attribute__((address_space(3))) void*)(dst + ii * 256),  // 4 rows = 1 KB
            16, 0, 0);
    }
}

// ---------------- Kernel 3: time-chunk-parallel per-channel scan ----------------
// 1 wave/block, 64 channels/block. Input staged through double-buffered LDS
// tiles (coalesced 256B-granule fetch) with counted vmcnt(16) so the next
// tile's loads stay in flight across 4 compute iterations. XCD-swizzled
// block mapping: XCD x owns chunks [8x, 8x+8) so warmup re-reads hit L2.
__global__ __launch_bounds__(64) void scan_kernel(const float* __restrict__ inp,
                                                  const float* __restrict__ cm,
                                                  float* __restrict__ out) {
    __shared__ float lds[2][64][TILE];               // 32 KB -> 4 blocks/CU

    const int id   = blockIdx.x;                     // 0..1023
    const int k    = ((id & 7) << 3) | ((id >> 3) & 7);  // chunk; XCD id%8 gets 8 consecutive chunks
    const int ygrp = id >> 6;                        // channel group 0..15
    const int lane = threadIdx.x;                    // 0..63
    const int ch0  = ygrp * 64;
    const int c    = ch0 + lane;
    const int sw   = lane & 7;                       // read-side XOR (matches stage)

    const int t0   = k * CHUNK;
    const int tend = min(t0 + CHUNK, NSTEPS);        // last chunk: 240 steps
    const int tw   = (k == 0) ? 0 : t0 - WARM;       // warmup start
    const int base = tw - PAD;                       // global col of tile0 float 0
    const int span = tend - tw + 16;                 // floats needed from base
    const int ntiles = (span + TILE - 1) / TILE;

    float* orow = out + (size_t)c * T_DIM;

    // prologue: stage tiles 0,1; wait tile 0 only (16 newest = tile 1 stay in flight)
    stage_tile(inp, ch0, base,        &lds[0][0][0], lane);
    stage_tile(inp, ch0, base + TILE, &lds[1][0][0], lane);
    asm volatile("s_waitcnt vmcnt(16)" ::: "memory");

    // init window: xs = inp_padded[c, tw..tw+15] (tile0 floats 0..15), ms = cm[tw..tw+15]
    float xs[16], ms[16];
    {
        const float4* lrow0 = (const float4*)&lds[0][lane][0];
        float4 i0 = lrow0[0 ^ sw];
        float4 i1 = lrow0[1 ^ sw];
        float4 i2 = lrow0[2 ^ sw];
        float4 i3 = lrow0[3 ^ sw];
        float tmp[16] = {i0.x,i0.y,i0.z,i0.w, i1.x,i1.y,i1.z,i1.w,
                         i2.x,i2.y,i2.z,i2.w, i3.x,i3.y,i3.z,i3.w};
        float4 m0 = *(const float4*)(cm + tw);
        float4 m1 = *(const float4*)(cm + tw + 4);
        float4 m2 = *(const float4*)(cm + tw + 8);
        float4 m3 = *(const float4*)(cm + tw + 12);
        float mt[16] = {m0.x,m0.y,m0.z,m0.w, m1.x,m1.y,m1.z,m1.w,
                        m2.x,m2.y,m2.z,m2.w, m3.x,m3.y,m3.z,m3.w};
        #pragma unroll
        for (int j = 0; j < 16; ++j) {
            xs[j] = (base + j < 0) ? 0.0f : tmp[j];  // left zero-pad (k==0 only)
            ms[j] = mt[j];
        }
    }
    float win = 0.0f;
    #pragma unroll
    for (int j = 0; j < 16; ++j) win = fmaf(xs[j], ms[j], win);

    float w = 1.0f, mem = 0.0f;   // exact for k==0; warmup-converged otherwise

    const int niter = (tend - tw) >> 4;
    for (int i = 0; i < niter; ++i) {
        const int t   = tw + (i << 4);
        const int nxt = i + 1;                       // data tile/offset consumed this iter

        if ((nxt & 3) == 0) {                        // crossing into tile tn
            const int tn = nxt >> 2;
            if (tn + 1 < ntiles) {
                // overwrite buffer holding tile tn-1 (fully consumed last iter)
                stage_tile(inp, ch0, base + (tn + 1) * TILE, &lds[(tn + 1) & 1][0][0], lane);
                asm volatile("s_waitcnt vmcnt(16)" ::: "memory");   // tile tn drained; tn+1 in flight
            } else {
                asm volatile("s_waitcnt vmcnt(0)" ::: "memory");    // tail: drain everything
            }
        }

        // incoming 16 cols: row[t+8 .. t+23] = tile floats [nxt*16, nxt*16+16)
        const float4* lrow = (const float4*)&lds[(nxt >> 2) & 1][lane][0];
        const int qk = (nxt & 3) * 4;
        float4 a0 = lrow[(qk + 0) ^ sw];
        float4 a1 = lrow[(qk + 1) ^ sw];
        float4 a2 = lrow[(qk + 2) ^ sw];
        float4 a3 = lrow[(qk + 3) ^ sw];
        float4 b0 = *(const float4*)(cm + t + 16);   // broadcast, L1/L2-hot
        float4 b1 = *(const float4*)(cm + t + 20);
        float4 b2 = *(const float4*)(cm + t + 24);
        float4 b3 = *(const float4*)(cm + t + 28);

        float xn[16] = {a0.x,a0.y,a0.z,a0.w, a1.x,a1.y,a1.z,a1.w,
                        a2.x,a2.y,a2.z,a2.w, a3.x,a3.y,a3.z,a3.w};
        float mn[16] = {b0.x,b0.y,b0.z,b0.w, b1.x,b1.y,b1.z,b1.w,
                        b2.x,b2.y,b2.z,b2.w, b3.x,b3.y,b3.z,b3.w};

        float spk[16];
        #pragma unroll
        for (int j = 0; j < 16; ++j) {
            w = fminf(fmaxf(fmaf(0.5f, w, 0.5f * win), -1.0f), 3.0f);
            float x = xs[j];                         // inp_padded[c, t+j]
            float r = (mem > 1.0f) ? 1.0f : 0.0f;    // reset from previous mem
            mem = fmaf(0.95f, mem, fmaf(w, x, -r));
            spk[j] = (mem > 1.0f) ? 1.0f : 0.0f;
            win = fmaf(xn[j], mn[j], fmaf(-x, ms[j], win));  // slide window
            xs[j] = xn[j]; ms[j] = mn[j];
        }

        if (t >= t0) {   // wave-uniform: warmup iterations skip stores entirely
            vf4 s0 = {spk[0],  spk[1],  spk[2],  spk[3]};
            vf4 s1 = {spk[4],  spk[5],  spk[6],  spk[7]};
            vf4 s2 = {spk[8],  spk[9],  spk[10], spk[11]};
            vf4 s3 = {spk[12], spk[13], spk[14], spk[15]};
            __builtin_nontemporal_store(s0, (vf4*)(orow + t));
            __builtin_nontemporal_store(s1, (vf4*)(orow + t + 4));
            __builtin_nontemporal_store(s2, (vf4*)(orow + t + 8));
            __builtin_nontemporal_store(s3, (vf4*)(orow + t + 12));
        }
    }
}

extern "C" void kernel_launch(void* const* d_in, const int* in_sizes, int n_in,
                              void* d_out, int out_size, void* d_ws, size_t ws_size,
                              hipStream_t stream) {
    const float* inp = (const float*)d_in[0];
    float* out = (float*)d_out;
    double* part = (double*)d_ws;
    float* cm = (float*)((char*)d_ws + WS_CM_OFFSET);

    colsum_partial<<<dim3(64, 8), 64, 0, stream>>>(inp, part);
    colmean_tail<<<dim3(65), 256, 0, stream>>>(part, inp, cm, out);
    scan_kernel<<<dim3(NCHUNK * (C_CH / 64)), 64, 0, stream>>>(inp, cm, out);
}

// Round 3
// 158.585 us; speedup vs baseline: 1.6113x; 1.6113x over previous
//
#include <hip/hip_runtime.h>
#include <stdint.h>

#define C_CH   1024
#define T_DIM  16384
#define NSTEPS (T_DIM - 16)   // 16368
#define PAD    8
#define TP     (T_DIM + 16)   // padded time length 16400
#define CHUNK  256
#define NCHUNK 64             // 64*256 = 16384 >= 16368
#define WARM   256
#define TILE   64             // cols per LDS tile (256 B per row)

// ws layout:
//   [0, 8*T_DIM*sizeof(double))  : double partial[8][T_DIM]   (1 MiB)
//   [1 MiB, +TP*4)               : float  colmean[TP]
#define WS_CM_OFFSET (8u * T_DIM * sizeof(double))

// ---------------- Kernel 1: per-row-chunk column partial sums ----------------
__global__ __launch_bounds__(64) void colsum_partial(const float* __restrict__ inp,
                                                     double* __restrict__ part) {
    int col4 = (blockIdx.x * 64 + threadIdx.x) * 4;   // 0..16380 step 4
    int rc   = blockIdx.y;                            // 0..7 (row chunk of 128)
    const float* p = inp + (size_t)rc * 128 * T_DIM + col4;
    double ax = 0.0, ay = 0.0, az = 0.0, aw = 0.0;
    #pragma unroll 16
    for (int r = 0; r < 128; ++r) {
        float4 v = *(const float4*)(p + (size_t)r * T_DIM);
        ax += (double)v.x; ay += (double)v.y; az += (double)v.z; aw += (double)v.w;
    }
    double* q = part + (size_t)rc * T_DIM + col4;
    q[0] = ax; q[1] = ay; q[2] = az; q[3] = aw;
}

// ---------------- Kernel 2: reduce partials -> padded column means, + tail copy ----------------
__global__ void colmean_tail(const double* __restrict__ part, const float* __restrict__ inp,
                             float* __restrict__ cm, float* __restrict__ out) {
    int i = blockIdx.x * 256 + threadIdx.x;   // 0..16639
    if (i < TP) {
        float v = 0.0f;
        if (i >= PAD && i < T_DIM + PAD) {
            int col = i - PAD;
            double t = 0.0;
            #pragma unroll
            for (int r = 0; r < 8; ++r) t += part[(size_t)r * T_DIM + col];
            v = (float)(t * (1.0 / 1024.0));        // /1024 is exact
        }
        cm[i] = v;
    }
    if (i < C_CH * 16) {                       // tail columns NSTEPS..T_DIM-1
        int c = i >> 4, j = i & 15;
        size_t idx = (size_t)c * T_DIM + NSTEPS + j;
        out[idx] = inp[idx];
    }
}

// ---------------- scan helpers ----------------
// Stage one [64 rows][64 cols] tile into LDS via global_load_lds (size=16).
// Linear LDS dest; XOR bank-swizzle (chunk ^ (row&7)) applied on the per-lane
// GLOBAL source address (G21/m173), same XOR on the ds_read side.
__device__ __forceinline__ void stage_tile(const float* __restrict__ inp, int ch0,
                                           int col0, float* dst, int lane) {
    const int sub = lane >> 4;        // row within quad: 0..3
    const int ci  = lane & 15;        // 16B-chunk index within row: 0..15
    #pragma unroll
    for (int ii = 0; ii < 16; ++ii) {
        int r   = 4 * ii + sub;                       // tile row = channel offset
        int q   = ci ^ (r & 7);                       // logical chunk for this slot
        int col = col0 + q * 4;                       // global float column
        col = min(max(col, 0), T_DIM - 4);            // clamp (edge slots unused)
        const float* src = inp + (size_t)(ch0 + r) * T_DIM + col;
        __builtin_amdgcn_global_load_lds(
            (const __attribute__((address_space(1))) void*)src,
            (__attribute__((address_space(3))) void*)(dst + ii * 256),
            16, 0, 0);
    }
}

// ---------------- Kernel 3: time-chunk-parallel per-channel scan ----------------
// vmcnt stream = stage loads ONLY: cm lives in LDS (broadcast ds_read), spikes
// accumulate in 8 u32 bitmask VGPRs and are stored in one coalesced-ish phase
// at the end with regular (L2-merged) stores. vmcnt(16) at tile boundaries is
// therefore exact: current tile complete, next tile in flight.
__global__ __launch_bounds__(64) void scan_kernel(const float* __restrict__ inp,
                                                  const float* __restrict__ cm,
                                                  float* __restrict__ out) {
    __shared__ float tile[2][64][TILE];               // 32 KB
    __shared__ float cml[768];                        // 3 KB chunk-local colmeans

    const int id   = blockIdx.x;                      // 0..1023
    const int k    = ((id & 7) << 3) | ((id >> 3) & 7);  // XCD id%8 owns chunks [8x,8x+8)
    const int ygrp = id >> 6;                         // channel group 0..15
    const int lane = threadIdx.x;                     // 0..63
    const int ch0  = ygrp * 64;
    const int c    = ch0 + lane;
    const int sw   = lane & 7;                        // read-side XOR

    const int t0   = k * CHUNK;
    const int tend = min(t0 + CHUNK, NSTEPS);         // last chunk: 240 valid steps
    const int tw   = (k == 0) ? 0 : t0 - WARM;        // warmup start
    const int base = tw - PAD;                        // global col of tile0 float 0
    const int span = tend - tw + 24;                  // floats base..tend+15
    const int ntiles = (span + TILE - 1) / TILE;      // 5 (k==0) or 9

    // ---- prologue staging: cm slice (3 ops) + tiles 0,1 (16+16) ----
    #pragma unroll
    for (int ii = 0; ii < 3; ++ii) {
        int s   = ii * 64 + lane;                     // 16B slot
        int idx = min(tw + s * 4, TP - 4);            // clamp (over-stage unused)
        __builtin_amdgcn_global_load_lds(
            (const __attribute__((address_space(1))) void*)(cm + idx),
            (__attribute__((address_space(3))) void*)(cml + s * 4),
            16, 0, 0);
    }
    stage_tile(inp, ch0, base,        &tile[0][0][0], lane);
    stage_tile(inp, ch0, base + TILE, &tile[1][0][0], lane);
    asm volatile("s_waitcnt vmcnt(16)" ::: "memory"); // cm + tile0 done; tile1 in flight

    // ---- init window: xs = inp_padded[c, tw..tw+15], ms = cm[tw..tw+15] ----
    float xs[16], ms[16];
    {
        const float4* lr = (const float4*)&tile[0][lane][0];
        float4 i0 = lr[0 ^ sw], i1 = lr[1 ^ sw], i2 = lr[2 ^ sw], i3 = lr[3 ^ sw];
        float tmp[16] = {i0.x,i0.y,i0.z,i0.w, i1.x,i1.y,i1.z,i1.w,
                         i2.x,i2.y,i2.z,i2.w, i3.x,i3.y,i3.z,i3.w};
        const float4* cmr = (const float4*)&cml[0];
        float4 m0 = cmr[0], m1 = cmr[1], m2 = cmr[2], m3 = cmr[3];
        float mt[16] = {m0.x,m0.y,m0.z,m0.w, m1.x,m1.y,m1.z,m1.w,
                        m2.x,m2.y,m2.z,m2.w, m3.x,m3.y,m3.z,m3.w};
        #pragma unroll
        for (int j = 0; j < 16; ++j) {
            xs[j] = (base + j < 0) ? 0.0f : tmp[j];   // left zero-pad (k==0 only)
            ms[j] = mt[j];
        }
    }
    float win = 0.0f;
    #pragma unroll
    for (int j = 0; j < 16; ++j) win = fmaf(xs[j], ms[j], win);

    float w = 1.0f, mem = 0.0f;   // exact for k==0; warmup-converged otherwise

    // ---- warmup: exactly 16 iterations (k>0 only), no spike recording ----
    if (k > 0) {
        for (int i = 0; i < 16; ++i) {
            const int nxt = i + 1;
            if ((nxt & 3) == 0) {                     // crossing into tile tn = nxt>>2
                const int tn = nxt >> 2;              // 1..4; tn+1 <= 5 < ntiles(9)
                asm volatile("s_waitcnt lgkmcnt(0)" ::: "memory");  // buffer reads drained
                stage_tile(inp, ch0, base + (tn + 1) * TILE, &tile[(tn + 1) & 1][0][0], lane);
                asm volatile("s_waitcnt vmcnt(16)" ::: "memory");   // tile tn ready
            }
            const float4* lr = (const float4*)&tile[(nxt >> 2) & 1][lane][0];
            const int qk = (nxt & 3) * 4;
            float4 a0 = lr[(qk + 0) ^ sw], a1 = lr[(qk + 1) ^ sw],
                   a2 = lr[(qk + 2) ^ sw], a3 = lr[(qk + 3) ^ sw];
            const float4* cmr = (const float4*)&cml[(i + 1) * 16];  // t+16-tw
            float4 b0 = cmr[0], b1 = cmr[1], b2 = cmr[2], b3 = cmr[3];
            float xn[16] = {a0.x,a0.y,a0.z,a0.w, a1.x,a1.y,a1.z,a1.w,
                            a2.x,a2.y,a2.z,a2.w, a3.x,a3.y,a3.z,a3.w};
            float mn[16] = {b0.x,b0.y,b0.z,b0.w, b1.x,b1.y,b1.z,b1.w,
                            b2.x,b2.y,b2.z,b2.w, b3.x,b3.y,b3.z,b3.w};
            #pragma unroll
            for (int j = 0; j < 16; ++j) {
                w = fminf(fmaxf(fmaf(0.5f, w, 0.5f * win), -1.0f), 3.0f);
                float x = xs[j];
                float r = (mem > 1.0f) ? 1.0f : 0.0f;
                mem = fmaf(0.95f, mem, fmaf(w, x, -r));
                win = fmaf(xn[j], mn[j], fmaf(-x, ms[j], win));
                xs[j] = xn[j]; ms[j] = mn[j];
            }
        }
    }

    // ---- main: always 16 iterations; spikes -> static-indexed bitmask regs ----
    uint32_t sb[8] = {0, 0, 0, 0, 0, 0, 0, 0};
    const int wi = (k == 0) ? 0 : 16;                 // wi % 4 == 0
    #pragma unroll
    for (int q = 0; q < 16; ++q) {
        const int nxt = wi + q + 1;
        if (((q + 1) & 3) == 0) {                     // compile-time crossing test
            const int tn = nxt >> 2;
            asm volatile("s_waitcnt lgkmcnt(0)" ::: "memory");
            if (tn + 1 < ntiles) {
                stage_tile(inp, ch0, base + (tn + 1) * TILE, &tile[(tn + 1) & 1][0][0], lane);
                asm volatile("s_waitcnt vmcnt(16)" ::: "memory");
            } else {
                asm volatile("s_waitcnt vmcnt(0)" ::: "memory");    // drain last tile
            }
        }
        const float4* lr = (const float4*)&tile[(nxt >> 2) & 1][lane][0];
        const int qk = (nxt & 3) * 4;
        float4 a0 = lr[(qk + 0) ^ sw], a1 = lr[(qk + 1) ^ sw],
               a2 = lr[(qk + 2) ^ sw], a3 = lr[(qk + 3) ^ sw];
        const float4* cmr = (const float4*)&cml[(wi + q + 1) * 16];
        float4 b0 = cmr[0], b1 = cmr[1], b2 = cmr[2], b3 = cmr[3];
        float xn[16] = {a0.x,a0.y,a0.z,a0.w, a1.x,a1.y,a1.z,a1.w,
                        a2.x,a2.y,a2.z,a2.w, a3.x,a3.y,a3.z,a3.w};
        float mn[16] = {b0.x,b0.y,b0.z,b0.w, b1.x,b1.y,b1.z,b1.w,
                        b2.x,b2.y,b2.z,b2.w, b3.x,b3.y,b3.z,b3.w};
        uint32_t m16 = 0;
        #pragma unroll
        for (int j = 0; j < 16; ++j) {
            w = fminf(fmaxf(fmaf(0.5f, w, 0.5f * win), -1.0f), 3.0f);
            float x = xs[j];
            float r = (mem > 1.0f) ? 1.0f : 0.0f;     // reset from previous mem
            mem = fmaf(0.95f, mem, fmaf(w, x, -r));
            m16 |= (mem > 1.0f) ? (1u << j) : 0u;     // spike bit
            win = fmaf(xn[j], mn[j], fmaf(-x, ms[j], win));
            xs[j] = xn[j]; ms[j] = mn[j];
        }
        sb[q >> 1] |= m16 << ((q & 1) * 16);          // static index (q unrolled)
    }

    // ---- dump: expand bitmask -> floats, regular stores (L2 merges lines) ----
    float* orow = out + (size_t)c * T_DIM;
    const int ng = (tend - t0) >> 4;                  // 16, or 15 for last chunk
    #pragma unroll
    for (int g = 0; g < 16; ++g) {
        if (g < ng) {
            uint32_t bits = (sb[g >> 1] >> ((g & 1) * 16)) & 0xFFFFu;
            float f[16];
            #pragma unroll
            for (int j = 0; j < 16; ++j) f[j] = (bits & (1u << j)) ? 1.0f : 0.0f;
            float* p = orow + t0 + g * 16;
            *(float4*)(p)      = make_float4(f[0],  f[1],  f[2],  f[3]);
            *(float4*)(p + 4)  = make_float4(f[4],  f[5],  f[6],  f[7]);
            *(float4*)(p + 8)  = make_float4(f[8],  f[9],  f[10], f[11]);
            *(float4*)(p + 12) = make_float4(f[12], f[13], f[14], f[15]);
        }
    }
}

extern "C" void kernel_launch(void* const* d_in, const int* in_sizes, int n_in,
                              void* d_out, int out_size, void* d_ws, size_t ws_size,
                              hipStream_t stream) {
    const float* inp = (const float*)d_in[0];
    float* out = (float*)d_out;
    double* part = (double*)d_ws;
    float* cm = (float*)((char*)d_ws + WS_CM_OFFSET);

    colsum_partial<<<dim3(64, 8), 64, 0, stream>>>(inp, part);
    colmean_tail<<<dim3(65), 256, 0, stream>>>(part, inp, cm, out);
    scan_kernel<<<dim3(NCHUNK * (C_CH / 64)), 64, 0, stream>>>(inp, cm, out);
}

// Round 5
// 156.558 us; speedup vs baseline: 1.6322x; 1.0130x over previous
//
#include <hip/hip_runtime.h>
#include <stdint.h>

#define C_CH   1024
#define T_DIM  16384
#define NSTEPS (T_DIM - 16)   // 16368
#define PAD    8
#define TP     (T_DIM + 16)   // padded time length 16400
#define CHUNK  128
#define NCHUNK 128            // 128*128 = 16384 >= 16368
#define WARM   256
#define TILE   32             // cols per LDS tile (128 B per row)

// ws layout:
//   [0, 8*T_DIM*sizeof(double))  : double partial[8][T_DIM]   (1 MiB)
//   [1 MiB, +TP*4)               : float  colmean[TP]
#define WS_CM_OFFSET (8u * T_DIM * sizeof(double))

// ---------------- Kernel 1: per-row-chunk column partial sums ----------------
__global__ __launch_bounds__(64) void colsum_partial(const float* __restrict__ inp,
                                                     double* __restrict__ part) {
    int col4 = (blockIdx.x * 64 + threadIdx.x) * 4;   // 0..16380 step 4
    int rc   = blockIdx.y;                            // 0..7 (row chunk of 128)
    const float* p = inp + (size_t)rc * 128 * T_DIM + col4;
    double ax = 0.0, ay = 0.0, az = 0.0, aw = 0.0;
    #pragma unroll 16
    for (int r = 0; r < 128; ++r) {
        float4 v = *(const float4*)(p + (size_t)r * T_DIM);
        ax += (double)v.x; ay += (double)v.y; az += (double)v.z; aw += (double)v.w;
    }
    double* q = part + (size_t)rc * T_DIM + col4;
    q[0] = ax; q[1] = ay; q[2] = az; q[3] = aw;
}

// ---------------- Kernel 2: reduce partials -> padded column means, + tail copy ----------------
__global__ void colmean_tail(const double* __restrict__ part, const float* __restrict__ inp,
                             float* __restrict__ cm, float* __restrict__ out) {
    int i = blockIdx.x * 256 + threadIdx.x;   // 0..16639
    if (i < TP) {
        float v = 0.0f;
        if (i >= PAD && i < T_DIM + PAD) {
            int col = i - PAD;
            double t = 0.0;
            #pragma unroll
            for (int r = 0; r < 8; ++r) t += part[(size_t)r * T_DIM + col];
            v = (float)(t * (1.0 / 1024.0));        // /1024 is exact
        }
        cm[i] = v;
    }
    if (i < C_CH * 16) {                       // tail columns NSTEPS..T_DIM-1
        int c = i >> 4, j = i & 15;
        size_t idx = (size_t)c * T_DIM + NSTEPS + j;
        out[idx] = inp[idx];
    }
}

// ---------------- scan helpers ----------------
// Stage one [64 rows][32 cols] tile (8 KB) into LDS via global_load_lds(16B).
// Per instruction: 64 lanes x 16B = 1 KB = 8 consecutive rows' 128 B segments.
// Linear LDS dest; XOR bank-swizzle (chunk ^ (row&7)) applied on the per-lane
// GLOBAL source address (G21/m173), same XOR on the ds_read side.
__device__ __forceinline__ void stage_tile(const float* __restrict__ inp, int ch0,
                                           int col0, float* dst, int lane) {
    const int sub = lane >> 3;        // row within octet: 0..7
    const int ci  = lane & 7;         // 16B-chunk index within row: 0..7
    #pragma unroll
    for (int ii = 0; ii < 8; ++ii) {
        int r   = ii * 8 + sub;                       // tile row = channel offset
        int q   = ci ^ (r & 7);                       // logical chunk for this slot
        int col = col0 + q * 4;                       // global float column
        col = min(max(col, 0), T_DIM - 4);            // clamp (edge slots unused)
        const float* src = inp + (size_t)(ch0 + r) * T_DIM + col;
        __builtin_amdgcn_global_load_lds(
            (const __attribute__((address_space(1))) void*)src,
            (__attribute__((address_space(3))) void*)(dst + ii * 256),  // 8 rows = 1 KB
            16, 0, 0);
    }
}

// ---------------- Kernel 3: time-chunk-parallel per-channel scan ----------------
// CHUNK=128 -> 2048 one-wave blocks; LDS 18 KB/block -> 8 blocks/CU = 2
// waves/SIMD so another wave computes while this one sits at vmcnt(8).
// vmcnt stream = stage loads only; spikes in bitmask regs, dumped at end.
// tw is CLAMPED to >= 0 (k=1 would give tw=-128 -> OOB cm reads -> NaN win).
// tw==0 start (k<=2) is EXACT (reference initial state), so no convergence loss.
__global__ __launch_bounds__(64) void scan_kernel(const float* __restrict__ inp,
                                                  const float* __restrict__ cm,
                                                  float* __restrict__ out) {
    __shared__ float tile[2][64][TILE];               // 16 KB
    __shared__ float cml[512];                        // 2 KB chunk-local colmeans

    const int id   = blockIdx.x;                      // 0..2047
    const int k    = ((id & 7) << 4) | ((id >> 3) & 15);  // XCD id%8 owns chunks [16x,16x+16)
    const int ygrp = id >> 7;                         // channel group 0..15
    const int lane = threadIdx.x;                     // 0..63
    const int ch0  = ygrp * 64;
    const int c    = ch0 + lane;
    const int sw   = lane & 7;                        // read-side XOR

    const int t0   = k * CHUNK;
    const int tend = min(t0 + CHUNK, NSTEPS);         // last chunk: 112 valid steps
    const int tw   = (t0 >= WARM) ? (t0 - WARM) : 0;  // clamped warmup start
    const int nwu  = (t0 - tw) >> 4;                  // warmup iterations: 0, 8, or 16
    const int base = tw - PAD;                        // global col of tile0 float 0
    const int span = tend - tw + 24;                  // floats base..tend+15
    const int ntiles = (span + TILE - 1) / TILE;

    // ---- prologue staging: cm slice (2 ops) + tiles 0,1 (8+8) ----
    #pragma unroll
    for (int ii = 0; ii < 2; ++ii) {
        int s   = ii * 64 + lane;                     // 16B slot, 128 slots = 512 floats
        int idx = min(tw + s * 4, TP - 4);            // clamp (over-stage unused)
        __builtin_amdgcn_global_load_lds(
            (const __attribute__((address_space(1))) void*)(cm + idx),
            (__attribute__((address_space(3))) void*)(cml + s * 4),
            16, 0, 0);
    }
    stage_tile(inp, ch0, base,        &tile[0][0][0], lane);
    stage_tile(inp, ch0, base + TILE, &tile[1][0][0], lane);
    asm volatile("s_waitcnt vmcnt(8)" ::: "memory");  // cm + tile0 done; tile1 in flight

    // ---- init window: xs = inp_padded[c, tw..tw+15], ms = cm[tw..tw+15] ----
    float xs[16], ms[16];
    {
        const float4* lr = (const float4*)&tile[0][lane][0];
        float4 i0 = lr[0 ^ sw], i1 = lr[1 ^ sw], i2 = lr[2 ^ sw], i3 = lr[3 ^ sw];
        float tmp[16] = {i0.x,i0.y,i0.z,i0.w, i1.x,i1.y,i1.z,i1.w,
                         i2.x,i2.y,i2.z,i2.w, i3.x,i3.y,i3.z,i3.w};
        const float4* cmr = (const float4*)&cml[0];
        float4 m0 = cmr[0], m1 = cmr[1], m2 = cmr[2], m3 = cmr[3];
        float mt[16] = {m0.x,m0.y,m0.z,m0.w, m1.x,m1.y,m1.z,m1.w,
                        m2.x,m2.y,m2.z,m2.w, m3.x,m3.y,m3.z,m3.w};
        #pragma unroll
        for (int j = 0; j < 16; ++j) {
            xs[j] = (base + j < 0) ? 0.0f : tmp[j];   // left zero-pad (tw==0 chunks)
            ms[j] = mt[j];
        }
    }
    float win = 0.0f;
    #pragma unroll
    for (int j = 0; j < 16; ++j) win = fmaf(xs[j], ms[j], win);

    float w = 1.0f, mem = 0.0f;   // exact when tw==0; warmup-converged otherwise

    // ---- warmup: nwu iterations (0/8/16), no spike recording ----
    for (int i = 0; i < nwu; ++i) {
        const int nxt = i + 1;                        // data tile-offset consumed
        if ((nxt & 1) == 0) {                         // entering tile tn = nxt>>1
            const int tn = nxt >> 1;                  // stage tn+1 (< ntiles always here)
            asm volatile("s_waitcnt lgkmcnt(0)" ::: "memory");
            stage_tile(inp, ch0, base + (tn + 1) * TILE, &tile[(tn + 1) & 1][0][0], lane);
            asm volatile("s_waitcnt vmcnt(8)" ::: "memory");    // tile tn ready
        }
        const float4* lr = (const float4*)&tile[(nxt >> 1) & 1][lane][0];
        const int qk = (nxt & 1) * 4;
        float4 a0 = lr[(qk + 0) ^ sw], a1 = lr[(qk + 1) ^ sw],
               a2 = lr[(qk + 2) ^ sw], a3 = lr[(qk + 3) ^ sw];
        const float4* cmr = (const float4*)&cml[(i + 1) * 16];
        float4 b0 = cmr[0], b1 = cmr[1], b2 = cmr[2], b3 = cmr[3];
        float xn[16] = {a0.x,a0.y,a0.z,a0.w, a1.x,a1.y,a1.z,a1.w,
                        a2.x,a2.y,a2.z,a2.w, a3.x,a3.y,a3.z,a3.w};
        float mn[16] = {b0.x,b0.y,b0.z,b0.w, b1.x,b1.y,b1.z,b1.w,
                        b2.x,b2.y,b2.z,b2.w, b3.x,b3.y,b3.z,b3.w};
        #pragma unroll
        for (int j = 0; j < 16; ++j) {
            w = fminf(fmaxf(fmaf(0.5f, w, 0.5f * win), -1.0f), 3.0f);
            float x = xs[j];
            float r = (mem > 1.0f) ? 1.0f : 0.0f;
            mem = fmaf(0.95f, mem, fmaf(w, x, -r));
            win = fmaf(xn[j], mn[j], fmaf(-x, ms[j], win));
            xs[j] = xn[j]; ms[j] = mn[j];
        }
    }

    // ---- main: 8 unrolled iterations; spikes -> static-indexed bitmask regs ----
    uint32_t sb[4] = {0, 0, 0, 0};
    const int wi = nwu;                               // even -> staging parity preserved
    #pragma unroll
    for (int q = 0; q < 8; ++q) {
        const int nxt = wi + q + 1;
        if (((q + 1) & 1) == 0) {                     // compile-time parity test
            const int tn = nxt >> 1;
            asm volatile("s_waitcnt lgkmcnt(0)" ::: "memory");
            if (tn + 1 < ntiles) {
                stage_tile(inp, ch0, base + (tn + 1) * TILE, &tile[(tn + 1) & 1][0][0], lane);
                asm volatile("s_waitcnt vmcnt(8)" ::: "memory");
            } else {
                asm volatile("s_waitcnt vmcnt(0)" ::: "memory");    // drain tail
            }
        }
        const float4* lr = (const float4*)&tile[(nxt >> 1) & 1][lane][0];
        const int qk = (nxt & 1) * 4;
        float4 a0 = lr[(qk + 0) ^ sw], a1 = lr[(qk + 1) ^ sw],
               a2 = lr[(qk + 2) ^ sw], a3 = lr[(qk + 3) ^ sw];
        const float4* cmr = (const float4*)&cml[(wi + q + 1) * 16];
        float4 b0 = cmr[0], b1 = cmr[1], b2 = cmr[2], b3 = cmr[3];
        float xn[16] = {a0.x,a0.y,a0.z,a0.w, a1.x,a1.y,a1.z,a1.w,
                        a2.x,a2.y,a2.z,a2.w, a3.x,a3.y,a3.z,a3.w};
        float mn[16] = {b0.x,b0.y,b0.z,b0.w, b1.x,b1.y,b1.z,b1.w,
                        b2.x,b2.y,b2.z,b2.w, b3.x,b3.y,b3.z,b3.w};
        uint32_t m16 = 0;
        #pragma unroll
        for (int j = 0; j < 16; ++j) {
            w = fminf(fmaxf(fmaf(0.5f, w, 0.5f * win), -1.0f), 3.0f);
            float x = xs[j];
            float r = (mem > 1.0f) ? 1.0f : 0.0f;     // reset from previous mem
            mem = fmaf(0.95f, mem, fmaf(w, x, -r));
            m16 |= (mem > 1.0f) ? (1u << j) : 0u;     // spike bit
            win = fmaf(xn[j], mn[j], fmaf(-x, ms[j], win));
            xs[j] = xn[j]; ms[j] = mn[j];
        }
        sb[q >> 1] |= m16 << ((q & 1) * 16);          // static index (q unrolled)
    }

    // ---- dump: expand bitmask -> floats, regular stores (L2 merges lines) ----
    float* orow = out + (size_t)c * T_DIM;
    const int ng = (tend - t0) >> 4;                  // 8, or 7 for last chunk
    #pragma unroll
    for (int g = 0; g < 8; ++g) {
        if (g < ng) {
            uint32_t bits = (sb[g >> 1] >> ((g & 1) * 16)) & 0xFFFFu;
            float f[16];
            #pragma unroll
            for (int j = 0; j < 16; ++j) f[j] = (bits & (1u << j)) ? 1.0f : 0.0f;
            float* p = orow + t0 + g * 16;
            *(float4*)(p)      = make_float4(f[0],  f[1],  f[2],  f[3]);
            *(float4*)(p + 4)  = make_float4(f[4],  f[5],  f[6],  f[7]);
            *(float4*)(p + 8)  = make_float4(f[8],  f[9],  f[10], f[11]);
            *(float4*)(p + 12) = make_float4(f[12], f[13], f[14], f[15]);
        }
    }
}

extern "C" void kernel_launch(void* const* d_in, const int* in_sizes, int n_in,
                              void* d_out, int out_size, void* d_ws, size_t ws_size,
                              hipStream_t stream) {
    const float* inp = (const float*)d_in[0];
    float* out = (float*)d_out;
    double* part = (double*)d_ws;
    float* cm = (float*)((char*)d_ws + WS_CM_OFFSET);

    colsum_partial<<<dim3(64, 8), 64, 0, stream>>>(inp, part);
    colmean_tail<<<dim3(65), 256, 0, stream>>>(part, inp, cm, out);
    scan_kernel<<<dim3(NCHUNK * (C_CH / 64)), 64, 0, stream>>>(inp, cm, out);
}

// Round 6
// 155.241 us; speedup vs baseline: 1.6460x; 1.0085x over previous
//
#include <hip/hip_runtime.h>
#include <stdint.h>

#define C_CH   1024
#define T_DIM  16384
#define NSTEPS (T_DIM - 16)   // 16368
#define PAD    8
#define TP     (T_DIM + 16)   // padded time length 16400
#define CHUNK  256
#define NCHUNK 64             // 64*256 = 16384 >= 16368
#define WARM   256
#define TILE   32             // cols per LDS tile (128 B per row)

// ws layout:
//   [0, 8*T_DIM*sizeof(double))  : double partial[8][T_DIM]   (1 MiB)
//   [1 MiB, +TP*4)               : float  colmean[TP]
#define WS_CM_OFFSET (8u * T_DIM * sizeof(double))

// ---------------- Kernel 1: per-row-chunk column partial sums ----------------
__global__ __launch_bounds__(64) void colsum_partial(const float* __restrict__ inp,
                                                     double* __restrict__ part) {
    int col4 = (blockIdx.x * 64 + threadIdx.x) * 4;   // 0..16380 step 4
    int rc   = blockIdx.y;                            // 0..7 (row chunk of 128)
    const float* p = inp + (size_t)rc * 128 * T_DIM + col4;
    double ax = 0.0, ay = 0.0, az = 0.0, aw = 0.0;
    #pragma unroll 16
    for (int r = 0; r < 128; ++r) {
        float4 v = *(const float4*)(p + (size_t)r * T_DIM);
        ax += (double)v.x; ay += (double)v.y; az += (double)v.z; aw += (double)v.w;
    }
    double* q = part + (size_t)rc * T_DIM + col4;
    q[0] = ax; q[1] = ay; q[2] = az; q[3] = aw;
}

// ---------------- Kernel 2: reduce partials -> padded column means, + tail copy ----------------
__global__ void colmean_tail(const double* __restrict__ part, const float* __restrict__ inp,
                             float* __restrict__ cm, float* __restrict__ out) {
    int i = blockIdx.x * 256 + threadIdx.x;   // 0..16639
    if (i < TP) {
        float v = 0.0f;
        if (i >= PAD && i < T_DIM + PAD) {
            int col = i - PAD;
            double t = 0.0;
            #pragma unroll
            for (int r = 0; r < 8; ++r) t += part[(size_t)r * T_DIM + col];
            v = (float)(t * (1.0 / 1024.0));        // /1024 is exact
        }
        cm[i] = v;
    }
    if (i < C_CH * 16) {                       // tail columns NSTEPS..T_DIM-1
        int c = i >> 4, j = i & 15;
        size_t idx = (size_t)c * T_DIM + NSTEPS + j;
        out[idx] = inp[idx];
    }
}

// ---------------- scan helpers ----------------
// Stage one [64 rows][32 cols] tile (8 KB) into LDS via global_load_lds(16B).
// Per instruction: 64 lanes x 16B = 1 KB = 8 consecutive rows' 128 B segments.
// Linear LDS dest; XOR bank-swizzle (chunk ^ (row&7)) applied on the per-lane
// GLOBAL source address (G21/m173), same XOR on the ds_read side.
__device__ __forceinline__ void stage_tile(const float* __restrict__ inp, int ch0,
                                           int col0, float* dst, int lane) {
    const int sub = lane >> 3;        // row within octet: 0..7
    const int ci  = lane & 7;         // 16B-chunk index within row: 0..7
    #pragma unroll
    for (int ii = 0; ii < 8; ++ii) {
        int r   = ii * 8 + sub;                       // tile row = channel offset
        int q   = ci ^ (r & 7);                       // logical chunk for this slot
        int col = col0 + q * 4;                       // global float column
        col = min(max(col, 0), T_DIM - 4);            // clamp (edge slots unused)
        const float* src = inp + (size_t)(ch0 + r) * T_DIM + col;
        __builtin_amdgcn_global_load_lds(
            (const __attribute__((address_space(1))) void*)src,
            (__attribute__((address_space(3))) void*)(dst + ii * 256),  // 8 rows = 1 KB
            16, 0, 0);
    }
}

// ---------------- Kernel 3: time-chunk-parallel per-channel scan ----------------
// DEPTH-3 tile pipeline: triple-buffered 8 KB tiles; at each 2-iteration
// boundary stage tile tn+2 and wait vmcnt(16) -> the tile about to be read
// was staged TWO groups (~1600 cyc) ago, exceeding HBM/L3 DMA latency
// (~900-1000 cyc back-solved from round-5 VALUBusy). vmcnt stream = stage
// loads only; spikes in bitmask regs, dumped at end with regular stores.
__global__ __launch_bounds__(64) void scan_kernel(const float* __restrict__ inp,
                                                  const float* __restrict__ cm,
                                                  float* __restrict__ out) {
    __shared__ float tile[3][64][TILE];               // 24 KB
    __shared__ float cml[768];                        // 3 KB chunk-local colmeans

    const int id   = blockIdx.x;                      // 0..1023
    const int k    = ((id & 7) << 3) | ((id >> 3) & 7);   // XCD id%8 owns chunks [8x,8x+8)
    const int ygrp = id >> 6;                         // channel group 0..15
    const int lane = threadIdx.x;                     // 0..63
    const int ch0  = ygrp * 64;
    const int c    = ch0 + lane;
    const int sw   = lane & 7;                        // read-side XOR

    const int t0   = k * CHUNK;
    const int tend = min(t0 + CHUNK, NSTEPS);         // last chunk: 240 valid steps
    const int tw   = (k == 0) ? 0 : t0 - WARM;        // >= 0 always (CHUNK == WARM)
    const int base = tw - PAD;                        // global col of tile0 float 0
    const int span = tend - tw + 24;                  // floats base..tend+15
    const int ntiles = (span + TILE - 1) / TILE;      // 9 (k==0) or 17

    // ---- prologue staging: cm slice (3 ops) + tiles 0,1,2 (8 each) ----
    #pragma unroll
    for (int ii = 0; ii < 3; ++ii) {
        int s   = ii * 64 + lane;                     // 16B slot, 192 slots = 768 floats
        int idx = min(tw + s * 4, TP - 4);            // clamp (over-stage unused)
        __builtin_amdgcn_global_load_lds(
            (const __attribute__((address_space(1))) void*)(cm + idx),
            (__attribute__((address_space(3))) void*)(cml + s * 4),
            16, 0, 0);
    }
    stage_tile(inp, ch0, base,            &tile[0][0][0], lane);
    stage_tile(inp, ch0, base + TILE,     &tile[1][0][0], lane);
    stage_tile(inp, ch0, base + 2 * TILE, &tile[2][0][0], lane);
    asm volatile("s_waitcnt vmcnt(16)" ::: "memory"); // cm + tile0 done; tiles 1,2 in flight

    // ---- init window: xs = inp_padded[c, tw..tw+15], ms = cm[tw..tw+15] ----
    float xs[16], ms[16];
    {
        const float4* lr = (const float4*)&tile[0][lane][0];
        float4 i0 = lr[0 ^ sw], i1 = lr[1 ^ sw], i2 = lr[2 ^ sw], i3 = lr[3 ^ sw];
        float tmp[16] = {i0.x,i0.y,i0.z,i0.w, i1.x,i1.y,i1.z,i1.w,
                         i2.x,i2.y,i2.z,i2.w, i3.x,i3.y,i3.z,i3.w};
        const float4* cmr = (const float4*)&cml[0];
        float4 m0 = cmr[0], m1 = cmr[1], m2 = cmr[2], m3 = cmr[3];
        float mt[16] = {m0.x,m0.y,m0.z,m0.w, m1.x,m1.y,m1.z,m1.w,
                        m2.x,m2.y,m2.z,m2.w, m3.x,m3.y,m3.z,m3.w};
        #pragma unroll
        for (int j = 0; j < 16; ++j) {
            xs[j] = (base + j < 0) ? 0.0f : tmp[j];   // left zero-pad (k==0 only)
            ms[j] = mt[j];
        }
    }
    float win = 0.0f;
    #pragma unroll
    for (int j = 0; j < 16; ++j) win = fmaf(xs[j], ms[j], win);

    float w = 1.0f, mem = 0.0f, spf = 0.0f;  // exact when tw==0; warmup-converged otherwise

    // ---- warmup: 16 iterations (k>0 only), no spike recording ----
    if (k > 0) {
        for (int i = 0; i < 16; ++i) {
            const int nxt = i + 1;                    // tile-offset consumed this iter
            if ((nxt & 1) == 0) {                     // entering tile tn = nxt>>1
                const int tn = nxt >> 1;              // 1..8; tn+2 <= 10 < 17 always
                asm volatile("s_waitcnt lgkmcnt(0)" ::: "memory");
                stage_tile(inp, ch0, base + (tn + 2) * TILE, &tile[(tn + 2) % 3][0][0], lane);
                asm volatile("s_waitcnt vmcnt(16)" ::: "memory");   // tile tn ready
            }
            const float4* lr = (const float4*)&tile[(nxt >> 1) % 3][lane][0];
            const int qk = (nxt & 1) * 4;
            float4 a0 = lr[(qk + 0) ^ sw], a1 = lr[(qk + 1) ^ sw],
                   a2 = lr[(qk + 2) ^ sw], a3 = lr[(qk + 3) ^ sw];
            const float4* cmr = (const float4*)&cml[(i + 1) * 16];
            float4 b0 = cmr[0], b1 = cmr[1], b2 = cmr[2], b3 = cmr[3];
            float xn[16] = {a0.x,a0.y,a0.z,a0.w, a1.x,a1.y,a1.z,a1.w,
                            a2.x,a2.y,a2.z,a2.w, a3.x,a3.y,a3.z,a3.w};
            float mn[16] = {b0.x,b0.y,b0.z,b0.w, b1.x,b1.y,b1.z,b1.w,
                            b2.x,b2.y,b2.z,b2.w, b3.x,b3.y,b3.z,b3.w};
            #pragma unroll
            for (int j = 0; j < 16; ++j) {
                w = fminf(fmaxf(fmaf(0.5f, w, 0.5f * win), -1.0f), 3.0f);
                float x = xs[j];
                mem = fmaf(0.95f, mem, fmaf(w, x, -spf));   // spf = prev spike = reset
                spf = (mem > 1.0f) ? 1.0f : 0.0f;
                win = fmaf(xn[j], mn[j], fmaf(-x, ms[j], win));
                xs[j] = xn[j]; ms[j] = mn[j];
            }
        }
    }

    // ---- main: 16 unrolled iterations; spikes -> static-indexed bitmask regs ----
    uint32_t sb[8] = {0, 0, 0, 0, 0, 0, 0, 0};
    const int wi = (k == 0) ? 0 : 16;                 // even -> parity preserved
    #pragma unroll
    for (int q = 0; q < 16; ++q) {
        const int nxt = wi + q + 1;
        if (((q + 1) & 1) == 0) {                     // compile-time parity test
            const int tn = nxt >> 1;
            asm volatile("s_waitcnt lgkmcnt(0)" ::: "memory");
            if (tn + 2 < ntiles) {
                stage_tile(inp, ch0, base + (tn + 2) * TILE, &tile[(tn + 2) % 3][0][0], lane);
                asm volatile("s_waitcnt vmcnt(16)" ::: "memory");   // tile tn ready
            } else if (tn + 1 < ntiles) {
                asm volatile("s_waitcnt vmcnt(8)" ::: "memory");    // tn done; tn+1 in flight
            } else {
                asm volatile("s_waitcnt vmcnt(0)" ::: "memory");    // drain tail
            }
        }
        const float4* lr = (const float4*)&tile[(nxt >> 1) % 3][lane][0];
        const int qk = (nxt & 1) * 4;
        float4 a0 = lr[(qk + 0) ^ sw], a1 = lr[(qk + 1) ^ sw],
               a2 = lr[(qk + 2) ^ sw], a3 = lr[(qk + 3) ^ sw];
        const float4* cmr = (const float4*)&cml[(wi + q + 1) * 16];
        float4 b0 = cmr[0], b1 = cmr[1], b2 = cmr[2], b3 = cmr[3];
        float xn[16] = {a0.x,a0.y,a0.z,a0.w, a1.x,a1.y,a1.z,a1.w,
                        a2.x,a2.y,a2.z,a2.w, a3.x,a3.y,a3.z,a3.w};
        float mn[16] = {b0.x,b0.y,b0.z,b0.w, b1.x,b1.y,b1.z,b1.w,
                        b2.x,b2.y,b2.z,b2.w, b3.x,b3.y,b3.z,b3.w};
        uint32_t m16 = 0;
        #pragma unroll
        for (int j = 0; j < 16; ++j) {
            w = fminf(fmaxf(fmaf(0.5f, w, 0.5f * win), -1.0f), 3.0f);
            float x = xs[j];
            mem = fmaf(0.95f, mem, fmaf(w, x, -spf));     // spf = prev spike = reset
            bool sp = (mem > 1.0f);
            spf = sp ? 1.0f : 0.0f;
            m16 |= sp ? (1u << j) : 0u;                   // spike bit
            win = fmaf(xn[j], mn[j], fmaf(-x, ms[j], win));
            xs[j] = xn[j]; ms[j] = mn[j];
        }
        sb[q >> 1] |= m16 << ((q & 1) * 16);              // static index (q unrolled)
    }

    // ---- dump: expand bitmask -> floats, regular stores (L2 merges lines) ----
    float* orow = out + (size_t)c * T_DIM;
    const int ng = (tend - t0) >> 4;                  // 16, or 15 for last chunk
    #pragma unroll
    for (int g = 0; g < 16; ++g) {
        if (g < ng) {
            uint32_t bits = (sb[g >> 1] >> ((g & 1) * 16)) & 0xFFFFu;
            float f[16];
            #pragma unroll
            for (int j = 0; j < 16; ++j) f[j] = (bits & (1u << j)) ? 1.0f : 0.0f;
            float* p = orow + t0 + g * 16;
            *(float4*)(p)      = make_float4(f[0],  f[1],  f[2],  f[3]);
            *(float4*)(p + 4)  = make_float4(f[4],  f[5],  f[6],  f[7]);
            *(float4*)(p + 8)  = make_float4(f[8],  f[9],  f[10], f[11]);
            *(float4*)(p + 12) = make_float4(f[12], f[13], f[14], f[15]);
        }
    }
}

extern "C" void kernel_launch(void* const* d_in, const int* in_sizes, int n_in,
                              void* d_out, int out_size, void* d_ws, size_t ws_size,
                              hipStream_t stream) {
    const float* inp = (const float*)d_in[0];
    float* out = (float*)d_out;
    double* part = (double*)d_ws;
    float* cm = (float*)((char*)d_ws + WS_CM_OFFSET);

    colsum_partial<<<dim3(64, 8), 64, 0, stream>>>(inp, part);
    colmean_tail<<<dim3(65), 256, 0, stream>>>(part, inp, cm, out);
    scan_kernel<<<dim3(NCHUNK * (C_CH / 64)), 64, 0, stream>>>(inp, cm, out);
}

// Round 7
// 154.348 us; speedup vs baseline: 1.6555x; 1.0058x over previous
//
#include <hip/hip_runtime.h>
#include <stdint.h>

#define C_CH   1024
#define T_DIM  16384
#define NSTEPS (T_DIM - 16)   // 16368
#define PAD    8
#define TP     (T_DIM + 16)   // padded time length 16400
#define SEG    256            // time steps per lane

// ws layout:
//   [0, 8*T_DIM*sizeof(double))  : double partial[8][T_DIM]   (1 MiB)
//   [1 MiB, +TP*4)               : float  colmean[TP]
#define WS_CM_OFFSET (8u * T_DIM * sizeof(double))

// ---------------- Kernel 1: per-row-chunk column partial sums ----------------
__global__ __launch_bounds__(64) void colsum_partial(const float* __restrict__ inp,
                                                     double* __restrict__ part) {
    int col4 = (blockIdx.x * 64 + threadIdx.x) * 4;   // 0..16380 step 4
    int rc   = blockIdx.y;                            // 0..7 (row chunk of 128)
    const float* p = inp + (size_t)rc * 128 * T_DIM + col4;
    double ax = 0.0, ay = 0.0, az = 0.0, aw = 0.0;
    #pragma unroll 32
    for (int r = 0; r < 128; ++r) {
        float4 v = *(const float4*)(p + (size_t)r * T_DIM);
        ax += (double)v.x; ay += (double)v.y; az += (double)v.z; aw += (double)v.w;
    }
    double* q = part + (size_t)rc * T_DIM + col4;
    q[0] = ax; q[1] = ay; q[2] = az; q[3] = aw;
}

// ---------------- Kernel 2: reduce partials -> padded column means, + tail copy ----------------
__global__ void colmean_tail(const double* __restrict__ part, const float* __restrict__ inp,
                             float* __restrict__ cm, float* __restrict__ out) {
    int i = blockIdx.x * 256 + threadIdx.x;   // 0..16639
    if (i < TP) {
        float v = 0.0f;
        if (i >= PAD && i < T_DIM + PAD) {
            int col = i - PAD;
            double t = 0.0;
            #pragma unroll
            for (int r = 0; r < 8; ++r) t += part[(size_t)r * T_DIM + col];
            v = (float)(t * (1.0 / 1024.0));        // /1024 is exact
        }
        cm[i] = v;
    }
    if (i < C_CH * 16) {                       // tail columns NSTEPS..T_DIM-1
        int c = i >> 4, j = i & 15;
        size_t idx = (size_t)c * T_DIM + NSTEPS + j;
        out[idx] = inp[idx];
    }
}

// ---------------- scan helpers ----------------
// Swizzled LDS read: raw row byte offset b (16B-aligned) -> swizzled address.
// Segment sigma = b>>10 (1 KB per lane-segment); 16B chunk index within the
// segment is XORed with (sigma & 7) -> a wave's 64 lanes (uniform chunk,
// lane-varying sigma) spread over 8 bank groups: 2-way aliasing = free (m136).
__device__ __forceinline__ float4 swz_ld(const float* base, int b) {
    int a = (b & ~1023) | ((((b >> 4) & 63) ^ ((b >> 10) & 7)) << 4);
    return *(const float4*)((const char*)base + a);
}

// ---------------- Kernel 3: row-parallel per-channel scan ----------------
// One block = one channel. Lane l owns time segment [256*l, 256*l+256).
// Entire 64 KB row staged ONCE via 64 coalesced 1 KB global_load_lds ops
// (contiguous stream; swizzle applied on the global source address per
// G21/m173, matching XOR on the ds_read side). Lane l's 256-step warmup
// region == lane l-1's segment -> already in LDS, zero extra HBM fetch.
// No in-loop staging: single vmcnt(0) after prologue. cm read from global
// (65 KB, L2-resident). Spikes -> bitmask regs -> LDS -> coalesced stores.
__global__ __launch_bounds__(64) void scan_kernel(const float* __restrict__ inp,
                                                  const float* __restrict__ cm,
                                                  float* __restrict__ out) {
    __shared__ float    rowl[T_DIM + 8];   // 64 KB row (swizzled) + 32 B zero pad
    __shared__ uint32_t bm[64][8];         // 2 KB spike bitmasks

    const int ch   = blockIdx.x;
    const int lane = threadIdx.x;
    const float* row  = inp + (size_t)ch * T_DIM;
    float*       orow = out + (size_t)ch * T_DIM;

    // ---- prologue: stage full row, swizzled source, linear LDS dest ----
    // Instr i covers segment i: lane lam fetches logical chunk (lam ^ (i&7)),
    // HW writes LDS at (uniform base) + lam*16.
    #pragma unroll
    for (int i = 0; i < 64; ++i) {
        const float* src = row + i * SEG + ((lane ^ (i & 7)) << 2);
        __builtin_amdgcn_global_load_lds(
            (const __attribute__((address_space(1))) void*)src,
            (__attribute__((address_space(3))) void*)(rowl + i * SEG),
            16, 0, 0);
    }
    if (lane < 2) {   // zero pad: raw [16384, 16392) (right zero-pad of inp_padded)
        *(float4*)(rowl + T_DIM + lane * 4) = make_float4(0.f, 0.f, 0.f, 0.f);
    }
    asm volatile("s_waitcnt vmcnt(0)" ::: "memory");
    __builtin_amdgcn_sched_barrier(0);

    // ---- init window at padded position sW (warmup start; main start for lane 0) ----
    const int sW = (lane == 0) ? 0 : (lane - 1) * SEG;
    const int sM = lane * SEG;

    float xs[16], ms[16];
    {
        const float4* cp = (const float4*)(cm + sW);
        float4 m0 = cp[0], m1 = cp[1], m2 = cp[2], m3 = cp[3];
        float mt[16] = {m0.x,m0.y,m0.z,m0.w, m1.x,m1.y,m1.z,m1.w,
                        m2.x,m2.y,m2.z,m2.w, m3.x,m3.y,m3.z,m3.w};
        #pragma unroll
        for (int j = 0; j < 16; ++j) ms[j] = mt[j];

        if (sW == 0) {                        // lanes 0,1: padded [0,16) = 8 zeros + raw[0,8)
            float4 x2 = swz_ld(rowl, 0);
            float4 x3 = swz_ld(rowl, 16);
            float xt[8] = {x2.x,x2.y,x2.z,x2.w, x3.x,x3.y,x3.z,x3.w};
            #pragma unroll
            for (int j = 0; j < 8; ++j) { xs[j] = 0.0f; xs[j + 8] = xt[j]; }
        } else {                              // raw [sW-8, sW+8)
            const int b = sW * 4 - 32;
            float4 x0 = swz_ld(rowl, b),      x1 = swz_ld(rowl, b + 16),
                   x2 = swz_ld(rowl, b + 32), x3 = swz_ld(rowl, b + 48);
            float xt[16] = {x0.x,x0.y,x0.z,x0.w, x1.x,x1.y,x1.z,x1.w,
                            x2.x,x2.y,x2.z,x2.w, x3.x,x3.y,x3.z,x3.w};
            #pragma unroll
            for (int j = 0; j < 16; ++j) xs[j] = xt[j];
        }
    }
    float win = 0.0f;
    #pragma unroll
    for (int j = 0; j < 16; ++j) win = fmaf(xs[j], ms[j], win);

    float w = 1.0f, mem = 0.0f, spf = 0.0f;   // exact for lane 0 (t=0); warmup-converged otherwise

    // ---- warmup: 16 iterations, lanes 1..63 only (lane 0 exec-masked) ----
    for (int it = 0; it < 16; ++it) {
        if (lane != 0) {
            const int b = sW * 4 + it * 64 + 32;          // raw bytes of padded [t+16, t+32)
            float4 a0 = swz_ld(rowl, b),      a1 = swz_ld(rowl, b + 16),
                   a2 = swz_ld(rowl, b + 32), a3 = swz_ld(rowl, b + 48);
            const float4* cp = (const float4*)(cm + sW + it * 16 + 16);
            float4 b0 = cp[0], b1 = cp[1], b2 = cp[2], b3 = cp[3];
            float xn[16] = {a0.x,a0.y,a0.z,a0.w, a1.x,a1.y,a1.z,a1.w,
                            a2.x,a2.y,a2.z,a2.w, a3.x,a3.y,a3.z,a3.w};
            float mn[16] = {b0.x,b0.y,b0.z,b0.w, b1.x,b1.y,b1.z,b1.w,
                            b2.x,b2.y,b2.z,b2.w, b3.x,b3.y,b3.z,b3.w};
            #pragma unroll
            for (int j = 0; j < 16; ++j) {
                w = fminf(fmaxf(fmaf(0.5f, w, 0.5f * win), -1.0f), 3.0f);
                float x = xs[j];
                mem = fmaf(0.95f, mem, fmaf(w, x, -spf));   // spf = prev spike = reset
                spf = (mem > 1.0f) ? 1.0f : 0.0f;
                win = fmaf(xn[j], mn[j], fmaf(-x, ms[j], win));
                xs[j] = xn[j]; ms[j] = mn[j];
            }
        }
    }

    // ---- main: 16 unrolled iterations, all lanes; spikes -> bitmask regs ----
    uint32_t sb[8] = {0, 0, 0, 0, 0, 0, 0, 0};
    #pragma unroll
    for (int q = 0; q < 16; ++q) {
        const int b = sM * 4 + q * 64 + 32;
        float4 a0 = swz_ld(rowl, b),      a1 = swz_ld(rowl, b + 16),
               a2 = swz_ld(rowl, b + 32), a3 = swz_ld(rowl, b + 48);
        const float4* cp = (const float4*)(cm + sM + q * 16 + 16);
        float4 b0 = cp[0], b1 = cp[1], b2 = cp[2], b3 = cp[3];
        float xn[16] = {a0.x,a0.y,a0.z,a0.w, a1.x,a1.y,a1.z,a1.w,
                        a2.x,a2.y,a2.z,a2.w, a3.x,a3.y,a3.z,a3.w};
        float mn[16] = {b0.x,b0.y,b0.z,b0.w, b1.x,b1.y,b1.z,b1.w,
                        b2.x,b2.y,b2.z,b2.w, b3.x,b3.y,b3.z,b3.w};
        uint32_t m16 = 0;
        #pragma unroll
        for (int j = 0; j < 16; ++j) {
            w = fminf(fmaxf(fmaf(0.5f, w, 0.5f * win), -1.0f), 3.0f);
            float x = xs[j];
            mem = fmaf(0.95f, mem, fmaf(w, x, -spf));       // spf = prev spike = reset
            bool sp = (mem > 1.0f);
            spf = sp ? 1.0f : 0.0f;
            m16 |= sp ? (1u << j) : 0u;
            win = fmaf(xn[j], mn[j], fmaf(-x, ms[j], win));
            xs[j] = xn[j]; ms[j] = mn[j];
        }
        sb[q >> 1] |= m16 << ((q & 1) * 16);                // static index (q unrolled)
    }

    // ---- write: bitmask transpose via LDS -> 64 coalesced 1 KB row stores ----
    *(uint4*)&bm[lane][0] = make_uint4(sb[0], sb[1], sb[2], sb[3]);
    *(uint4*)&bm[lane][4] = make_uint4(sb[4], sb[5], sb[6], sb[7]);
    // single-wave RAW on LDS: compiler inserts lgkmcnt ordering
    #pragma unroll 8
    for (int seg = 0; seg < 64; ++seg) {
        uint32_t word = bm[seg][lane >> 3];                 // step s = lane*4+e; word s>>5
        uint32_t bits = (word >> ((lane & 7) * 4)) & 0xFu;  // bit s&31
        float4 v = make_float4((bits & 1u) ? 1.f : 0.f, (bits & 2u) ? 1.f : 0.f,
                               (bits & 4u) ? 1.f : 0.f, (bits & 8u) ? 1.f : 0.f);
        if (seg < 63 || lane < 60)   // positions >= NSTEPS are input-copy (colmean_tail)
            *(float4*)(orow + seg * SEG + lane * 4) = v;
    }
}

extern "C" void kernel_launch(void* const* d_in, const int* in_sizes, int n_in,
                              void* d_out, int out_size, void* d_ws, size_t ws_size,
                              hipStream_t stream) {
    const float* inp = (const float*)d_in[0];
    float* out = (float*)d_out;
    double* part = (double*)d_ws;
    float* cm = (float*)((char*)d_ws + WS_CM_OFFSET);

    colsum_partial<<<dim3(64, 8), 64, 0, stream>>>(inp, part);
    colmean_tail<<<dim3(65), 256, 0, stream>>>(part, inp, cm, out);
    scan_kernel<<<dim3(C_CH), 64, 0, stream>>>(inp, cm, out);
}